// Round 1
// baseline (82.795 us; speedup 1.0000x reference)
//
#include <hip/hip_runtime.h>

// Quantum circuit expectation via Pauli-coefficient reduction.
// E(x) = sum_{t in {I,Z,Y}^4} A_t * prod_w r_w(t_w),
//   r_w(I)=1, r_w(Z)=cos(x_w), r_w(Y)=-sin(x_w),
//   A_t = Tr(M * kron sigma_{t_w})/16,  M = V^dag Z0 V,
// where V = the weights-only part of the circuit (Rot layers + CNOT rings).

struct c32 { float x, y; };
__device__ inline c32 cmul(c32 a, c32 b) { return { a.x*b.x - a.y*b.y, a.x*b.y + a.y*b.x }; }
__device__ inline c32 cadd(c32 a, c32 b) { return { a.x + b.x, a.y + b.y }; }

// One block, 256 threads. Computes A[81] into d_ws.
__global__ void qq_precompute(const float* __restrict__ wgt, float* __restrict__ A) {
    __shared__ c32 V[16][16];   // V[k][col] = amplitude k of V|col>
    __shared__ c32 Mm[16][16];  // M = V^dag Z0 V
    const int tid = threadIdx.x;

    if (tid < 16) {
        const int col = tid;
        c32 st[16];
#pragma unroll
        for (int k = 0; k < 16; ++k) st[k] = { 0.f, 0.f };
        st[col] = { 1.f, 0.f };

        // wire w <-> bit (8 >> w); wire 0 is MSB (matches (2,)*4 C-order flatten)
        for (int l = 0; l < 2; ++l) {
            for (int wi = 0; wi < 4; ++wi) {
                const float* wp = wgt + (l * 4 + wi) * 3;
                const float phi = wp[0], th = wp[1], om = wp[2];
                const float ct = cosf(0.5f * th), sth = sinf(0.5f * th);
                const float ap = 0.5f * (phi + om), am = 0.5f * (phi - om);
                const float cp = cosf(ap), sp = sinf(ap);
                const float cm = cosf(am), sm = sinf(am);
                // Rot = [[ep*c, -em*s],[conj(em)*s, conj(ep)*c]],
                // ep = exp(-i*ap), em = exp(+i*am)
                const c32 U00 = {  cp * ct, -sp * ct };
                const c32 U01 = { -cm * sth, -sm * sth };
                const c32 U10 = {  cm * sth, -sm * sth };
                const c32 U11 = {  cp * ct,  sp * ct };
                const int bit = 8 >> wi;
                for (int b = 0; b < 16; ++b) {
                    if (!(b & bit)) {
                        const c32 a0 = st[b], a1 = st[b | bit];
                        st[b]       = cadd(cmul(U00, a0), cmul(U01, a1));
                        st[b | bit] = cadd(cmul(U10, a0), cmul(U11, a1));
                    }
                }
            }
            const int r = (l == 0) ? 1 : 2;  // l % (n-1) + 1
            for (int wi = 0; wi < 4; ++wi) {
                const int cbit = 8 >> wi;
                const int tbit = 8 >> ((wi + r) & 3);
                for (int b = 0; b < 16; ++b) {
                    if ((b & cbit) && !(b & tbit)) {
                        const c32 tmp = st[b];
                        st[b] = st[b | tbit];
                        st[b | tbit] = tmp;
                    }
                }
            }
        }
#pragma unroll
        for (int k = 0; k < 16; ++k) V[k][col] = st[k];
    }
    __syncthreads();

    {   // M_{ij} = sum_k conj(V_{ki}) z_k V_{kj},  z_k = +1 if wire0 bit (k&8)==0 else -1
        const int i = tid >> 4, j = tid & 15;
        c32 acc = { 0.f, 0.f };
#pragma unroll
        for (int k = 0; k < 16; ++k) {
            const float z = (k & 8) ? -1.f : 1.f;
            const c32 vi = V[k][i], vj = V[k][j];
            acc.x += z * (vi.x * vj.x + vi.y * vj.y);
            acc.y += z * (vi.x * vj.y - vi.y * vj.x);
        }
        Mm[i][j] = acc;
    }
    __syncthreads();

    if (tid < 81) {
        const int t = tid;
        const int tw[4] = { t / 27, (t / 9) % 3, (t / 3) % 3, t % 3 };  // 0=I,1=Z,2=Y
        int maskY = 0, maskZY = 0, nY = 0;
#pragma unroll
        for (int w = 0; w < 4; ++w) {
            const int bit = 8 >> w;
            if (tw[w] == 2) { maskY |= bit; ++nY; }
            if (tw[w] != 0) maskZY |= bit;
        }
        // Tr(M S_t) = i^nY * sum_i (-1)^popc(i&maskZY) * M[i][i^maskY]
        float sx = 0.f, sy = 0.f;
        for (int i = 0; i < 16; ++i) {
            const float sgn = (__popc(i & maskZY) & 1) ? -1.f : 1.f;
            const c32 m = Mm[i][i ^ maskY];
            sx += sgn * m.x;
            sy += sgn * m.y;
        }
        float re;
        switch (nY & 3) {
            case 0:  re =  sx; break;
            case 1:  re = -sy; break;
            case 2:  re = -sx; break;
            default: re =  sy; break;
        }
        A[t] = re * (1.f / 16.f);
    }
}

__global__ __launch_bounds__(256) void qq_main(const float4* __restrict__ x,
                                               const float* __restrict__ A,
                                               float* __restrict__ out, int M) {
    const int i = blockIdx.x * 256 + threadIdx.x;
    if (i >= M) return;
    const float4 xv = x[i];
    float s0, c0, s1, c1, s2, c2, s3, c3;
    __sincosf(xv.x, &s0, &c0);
    __sincosf(xv.y, &s1, &c1);
    __sincosf(xv.z, &s2, &c2);
    __sincosf(xv.w, &s3, &c3);
    const float y0 = -s0, y1 = -s1, y2 = -s2, y3 = -s3;

    // t = ((t0*3 + t1)*3 + t2)*3 + t3 ; digit w pairs with wire w factors (1, c_w, y_w)
    float lvl0[3];
#pragma unroll
    for (int t0 = 0; t0 < 3; ++t0) {
        float lvl1[3];
#pragma unroll
        for (int t1 = 0; t1 < 3; ++t1) {
            float v[3];
#pragma unroll
            for (int t2 = 0; t2 < 3; ++t2) {
                const float* Ap = A + ((t0 * 3 + t1) * 3 + t2) * 3;
                v[t2] = fmaf(y3, Ap[2], fmaf(c3, Ap[1], Ap[0]));
            }
            lvl1[t1] = fmaf(y2, v[2], fmaf(c2, v[1], v[0]));
        }
        lvl0[t0] = fmaf(y1, lvl1[2], fmaf(c1, lvl1[1], lvl1[0]));
    }
    out[i] = fmaf(y0, lvl0[2], fmaf(c0, lvl0[1], lvl0[0]));
}

extern "C" void kernel_launch(void* const* d_in, const int* in_sizes, int n_in,
                              void* d_out, int out_size, void* d_ws, size_t ws_size,
                              hipStream_t stream) {
    const float* x = (const float*)d_in[0];      // (64, 8192, 4) f32
    const float* w = (const float*)d_in[1];      // (2, 4, 3) f32
    float* A = (float*)d_ws;                     // 81 floats scratch
    const int M = in_sizes[0] / 4;               // 524288 samples

    qq_precompute<<<1, 256, 0, stream>>>(w, A);
    qq_main<<<(M + 255) / 256, 256, 0, stream>>>((const float4*)x, A, (float*)d_out, M);
}

// Round 2
// 68.947 us; speedup vs baseline: 1.2008x; 1.2008x over previous
//
#include <hip/hip_runtime.h>

// Quantum circuit expectation via Pauli-coefficient reduction, fully fused.
// E(x) = sum_{t in {I,Z,Y}^4} A_t * prod_w r_w(t_w),
//   r_w(I)=1, r_w(Z)=cos(x_w), r_w(Y)=-sin(x_w),
//   A_t = Tr(M * kron sigma_{t_w})/16,  M = V^dag Z0 V,
// where V = weights-only part of the circuit (Rot layers + CNOT rings).
// Every block redundantly computes A[81] in LDS (~2k cycles), then contracts
// 4 samples/thread against it. One launch, no global scratch.

#define SPT 4  // samples per thread; block = 256 threads -> 1024 samples/block

struct c32 { float x, y; };
__device__ inline c32 cmul(c32 a, c32 b) { return { a.x*b.x - a.y*b.y, a.x*b.y + a.y*b.x }; }
__device__ inline c32 cadd(c32 a, c32 b) { return { a.x + b.x, a.y + b.y }; }

__global__ __launch_bounds__(256) void qq_fused(const float4* __restrict__ x,
                                                const float* __restrict__ wgt,
                                                float* __restrict__ out, int M) {
    __shared__ float trigC[24], trigS[24];
    __shared__ c32 V[16][16];   // V[k][col]
    __shared__ c32 Mm[16][16];  // M = V^dag Z0 V
    __shared__ float As[81];
    const int tid = threadIdx.x;

    // --- phase 1: all gate trig in parallel (24 lanes, fast sincos) ---
    if (tid < 24) {
        const int g = tid / 3, sel = tid - 3 * g;
        const float phi = wgt[g * 3 + 0], th = wgt[g * 3 + 1], om = wgt[g * 3 + 2];
        const float ang = (sel == 0) ? 0.5f * th
                        : (sel == 1) ? 0.5f * (phi + om)
                                     : 0.5f * (phi - om);
        __sincosf(ang, &trigS[tid], &trigC[tid]);
    }
    __syncthreads();

    // --- phase 2: simulate V columns (16 lanes, straight-line unrolled) ---
    if (tid < 16) {
        c32 st[16];
#pragma unroll
        for (int k = 0; k < 16; ++k) st[k] = { 0.f, 0.f };
        st[tid] = { 1.f, 0.f };

        // wire w <-> bit (8 >> w); wire 0 is MSB ((2,)*4 C-order flatten)
#pragma unroll
        for (int l = 0; l < 2; ++l) {
#pragma unroll
            for (int wi = 0; wi < 4; ++wi) {
                const int g = l * 4 + wi;
                const float ct = trigC[3 * g],     sth = trigS[3 * g];
                const float cp = trigC[3 * g + 1], sp  = trigS[3 * g + 1];
                const float cm = trigC[3 * g + 2], sm  = trigS[3 * g + 2];
                // Rot = [[ep*c, -em*s],[conj(em)*s, conj(ep)*c]],
                // ep = exp(-i*(phi+om)/2), em = exp(+i*(phi-om)/2)
                const c32 U00 = {  cp * ct,  -sp * ct  };
                const c32 U01 = { -cm * sth, -sm * sth };
                const c32 U10 = {  cm * sth, -sm * sth };
                const c32 U11 = {  cp * ct,   sp * ct  };
                const int bit = 8 >> wi;
#pragma unroll
                for (int b = 0; b < 16; ++b) {
                    if (!(b & bit)) {
                        const c32 a0 = st[b], a1 = st[b | bit];
                        st[b]       = cadd(cmul(U00, a0), cmul(U01, a1));
                        st[b | bit] = cadd(cmul(U10, a0), cmul(U11, a1));
                    }
                }
            }
            const int r = (l == 0) ? 1 : 2;  // l % (n-1) + 1
#pragma unroll
            for (int wi = 0; wi < 4; ++wi) {
                const int cbit = 8 >> wi;
                const int tbit = 8 >> ((wi + r) & 3);
#pragma unroll
                for (int b = 0; b < 16; ++b) {
                    if ((b & cbit) && !(b & tbit)) {
                        const c32 tmp = st[b];
                        st[b] = st[b | tbit];
                        st[b | tbit] = tmp;
                    }
                }
            }
        }
#pragma unroll
        for (int k = 0; k < 16; ++k) V[k][tid] = st[k];
    }
    __syncthreads();

    // --- phase 3: M_{ij} = sum_k conj(V_{ki}) z_k V_{kj} (256 lanes) ---
    {
        const int i = tid >> 4, j = tid & 15;
        c32 acc = { 0.f, 0.f };
#pragma unroll
        for (int k = 0; k < 16; ++k) {
            const float z = (k & 8) ? -1.f : 1.f;
            const c32 vi = V[k][i], vj = V[k][j];
            acc.x += z * (vi.x * vj.x + vi.y * vj.y);
            acc.y += z * (vi.x * vj.y - vi.y * vj.x);
        }
        Mm[i][j] = acc;
    }
    __syncthreads();

    // --- phase 4: Pauli coefficients A_t (81 lanes) ---
    if (tid < 81) {
        const int t = tid;
        const int tw[4] = { t / 27, (t / 9) % 3, (t / 3) % 3, t % 3 };  // 0=I,1=Z,2=Y
        int maskY = 0, maskZY = 0, nY = 0;
#pragma unroll
        for (int w = 0; w < 4; ++w) {
            const int bit = 8 >> w;
            if (tw[w] == 2) { maskY |= bit; ++nY; }
            if (tw[w] != 0) maskZY |= bit;
        }
        // Tr(M S_t) = i^nY * sum_i (-1)^popc(i&maskZY) * M[i][i^maskY]
        float sx = 0.f, sy = 0.f;
#pragma unroll
        for (int i = 0; i < 16; ++i) {
            const float sgn = (__popc(i & maskZY) & 1) ? -1.f : 1.f;
            const c32 m = Mm[i][i ^ maskY];
            sx += sgn * m.x;
            sy += sgn * m.y;
        }
        float re;
        switch (nY & 3) {
            case 0:  re =  sx; break;
            case 1:  re = -sy; break;
            case 2:  re = -sx; break;
            default: re =  sy; break;
        }
        As[t] = re * (1.f / 16.f);
    }
    __syncthreads();

    // --- phase 5: per-sample contraction, SPT samples/thread ---
    const int base = blockIdx.x * (256 * SPT) + tid;
    float4 xv[SPT];
#pragma unroll
    for (int s = 0; s < SPT; ++s) {
        const int idx = base + s * 256;
        xv[s] = (idx < M) ? x[idx] : make_float4(0.f, 0.f, 0.f, 0.f);
    }
    float c0[SPT], y0[SPT], c1[SPT], y1[SPT], c2[SPT], y2[SPT], c3[SPT], y3[SPT];
#pragma unroll
    for (int s = 0; s < SPT; ++s) {
        float sn;
        __sincosf(xv[s].x, &sn, &c0[s]); y0[s] = -sn;
        __sincosf(xv[s].y, &sn, &c1[s]); y1[s] = -sn;
        __sincosf(xv[s].z, &sn, &c2[s]); y2[s] = -sn;
        __sincosf(xv[s].w, &sn, &c3[s]); y3[s] = -sn;
    }

    float lvl0[SPT][3];
#pragma unroll
    for (int t0 = 0; t0 < 3; ++t0) {
        float lvl1[SPT][3];
#pragma unroll
        for (int t1 = 0; t1 < 3; ++t1) {
            float v[SPT][3];
#pragma unroll
            for (int t2 = 0; t2 < 3; ++t2) {
                const int b = ((t0 * 3 + t1) * 3 + t2) * 3;
                const float a0 = As[b], a1 = As[b + 1], a2 = As[b + 2];
#pragma unroll
                for (int s = 0; s < SPT; ++s)
                    v[s][t2] = fmaf(y3[s], a2, fmaf(c3[s], a1, a0));
            }
#pragma unroll
            for (int s = 0; s < SPT; ++s)
                lvl1[s][t1] = fmaf(y2[s], v[s][2], fmaf(c2[s], v[s][1], v[s][0]));
        }
#pragma unroll
        for (int s = 0; s < SPT; ++s)
            lvl0[s][t0] = fmaf(y1[s], lvl1[s][2], fmaf(c1[s], lvl1[s][1], lvl1[s][0]));
    }
#pragma unroll
    for (int s = 0; s < SPT; ++s) {
        const int idx = base + s * 256;
        if (idx < M)
            out[idx] = fmaf(y0[s], lvl0[s][2], fmaf(c0[s], lvl0[s][1], lvl0[s][0]));
    }
}

extern "C" void kernel_launch(void* const* d_in, const int* in_sizes, int n_in,
                              void* d_out, int out_size, void* d_ws, size_t ws_size,
                              hipStream_t stream) {
    const float* x = (const float*)d_in[0];      // (64, 8192, 4) f32
    const float* w = (const float*)d_in[1];      // (2, 4, 3) f32
    const int M = in_sizes[0] / 4;               // 524288 samples
    const int blocks = (M + 256 * SPT - 1) / (256 * SPT);
    qq_fused<<<blocks, 256, 0, stream>>>((const float4*)x, w, (float*)d_out, M);
}

// Round 3
// 62.701 us; speedup vs baseline: 1.3205x; 1.0996x over previous
//
#include <hip/hip_runtime.h>

// Quantum circuit expectation via Pauli-coefficient reduction, fully fused.
// E(x) = sum_{t in {I,Z,Y}^4} A_t * prod_w r_w(t_w),
//   r_w(I)=1, r_w(Z)=cos(x_w), r_w(Y)=-sin(x_w),
//   A_t = Tr(M * kron sigma_{t_w})/16,  M = V^dag Z0 V,
// where V = weights-only part of the circuit (Rot layers + CNOT rings).
// Preamble (A[81] in LDS) is computed redundantly per block with all 256
// lanes: thread (col,k) holds amplitude V[k][col]; gates are shfl_xor
// butterflies. x loads are issued before the preamble to overlap HBM latency.

#define SPT 4  // samples per thread; block = 256 threads -> 1024 samples/block

struct c32 { float x, y; };

__global__ __launch_bounds__(256) void qq_fused(const float4* __restrict__ x,
                                                const float* __restrict__ wgt,
                                                float* __restrict__ out, int M) {
    __shared__ float Ug[8][8];  // per-gate Rot matrix: U00r,U00i,U01r,U01i,U10r,U10i,U11r,U11i
    __shared__ c32 V[16][16];   // V[k][col]
    __shared__ c32 Mm[16][16];  // M = V^dag Z0 V
    __shared__ float As[81];
    const int tid = threadIdx.x;

    // --- issue sample loads first: HBM latency overlaps the preamble ---
    const int base = blockIdx.x * (256 * SPT) + tid;
    float4 xv[SPT];
#pragma unroll
    for (int s = 0; s < SPT; ++s) {
        const int idx = base + s * 256;
        xv[s] = (idx < M) ? x[idx] : make_float4(0.f, 0.f, 0.f, 0.f);
    }

    // --- phase 1: gate matrices (8 lanes, 3 fast sincos each) ---
    if (tid < 8) {
        const float* wp = wgt + tid * 3;
        const float phi = wp[0], th = wp[1], om = wp[2];
        float ct, sth, cp, sp, cm, sm;
        __sincosf(0.5f * th, &sth, &ct);
        __sincosf(0.5f * (phi + om), &sp, &cp);
        __sincosf(0.5f * (phi - om), &sm, &cm);
        // Rot = [[ep*c, -em*s],[conj(em)*s, conj(ep)*c]],
        // ep = exp(-i*(phi+om)/2), em = exp(+i*(phi-om)/2)
        Ug[tid][0] =  cp * ct;  Ug[tid][1] = -sp * ct;   // U00
        Ug[tid][2] = -cm * sth; Ug[tid][3] = -sm * sth;  // U01
        Ug[tid][4] =  cm * sth; Ug[tid][5] = -sm * sth;  // U10
        Ug[tid][6] =  cp * ct;  Ug[tid][7] =  sp * ct;   // U11
    }
    __syncthreads();

    // --- phase 2: simulate V, all 256 lanes; thread (col,k) holds V[k][col].
    // wire w <-> bit (8 >> w) of k; wire 0 is MSB ((2,)*4 C-order flatten).
    // shfl_xor masks <= 8 stay within the 16-lane amplitude group of a wave.
    {
        const int k = tid & 15;
        float ar = (k == (tid >> 4)) ? 1.f : 0.f, ai = 0.f;
#pragma unroll
        for (int l = 0; l < 2; ++l) {
#pragma unroll
            for (int wi = 0; wi < 4; ++wi) {
                const int g = l * 4 + wi, bit = 8 >> wi;
                const float u00r = Ug[g][0], u00i = Ug[g][1];
                const float u01r = Ug[g][2], u01i = Ug[g][3];
                const float u10r = Ug[g][4], u10i = Ug[g][5];
                const float u11r = Ug[g][6], u11i = Ug[g][7];
                const float pr = __shfl_xor(ar, bit);
                const float pi = __shfl_xor(ai, bit);
                const bool hi = (k & bit) != 0;
                const float uar = hi ? u11r : u00r, uai = hi ? u11i : u00i;
                const float upr = hi ? u10r : u01r, upi = hi ? u10i : u01i;
                const float nr = uar * ar - uai * ai + upr * pr - upi * pi;
                const float ni = uar * ai + uai * ar + upr * pi + upi * pr;
                ar = nr; ai = ni;
            }
            const int r = l ? 2 : 1;  // l % (n-1) + 1
#pragma unroll
            for (int wi = 0; wi < 4; ++wi) {
                const int cbit = 8 >> wi, tbit = 8 >> ((wi + r) & 3);
                const float pr = __shfl_xor(ar, tbit);
                const float pi = __shfl_xor(ai, tbit);
                if (k & cbit) { ar = pr; ai = pi; }
            }
        }
        V[k][tid >> 4] = { ar, ai };
    }
    __syncthreads();

    // --- phase 3: M_{ij} = sum_k conj(V_{ki}) z_k V_{kj} (256 lanes) ---
    {
        const int i = tid >> 4, j = tid & 15;
        float accx = 0.f, accy = 0.f;
#pragma unroll
        for (int k = 0; k < 16; ++k) {
            const float z = (k & 8) ? -1.f : 1.f;
            const c32 vi = V[k][i], vj = V[k][j];
            accx += z * (vi.x * vj.x + vi.y * vj.y);
            accy += z * (vi.x * vj.y - vi.y * vj.x);
        }
        Mm[i][j] = { accx, accy };
    }
    __syncthreads();

    // --- phase 4: Pauli coefficients A_t (81 lanes) ---
    if (tid < 81) {
        const int t = tid;
        const int tw[4] = { t / 27, (t / 9) % 3, (t / 3) % 3, t % 3 };  // 0=I,1=Z,2=Y
        int maskY = 0, maskZY = 0, nY = 0;
#pragma unroll
        for (int w = 0; w < 4; ++w) {
            const int bit = 8 >> w;
            if (tw[w] == 2) { maskY |= bit; ++nY; }
            if (tw[w] != 0) maskZY |= bit;
        }
        // Tr(M S_t) = i^nY * sum_i (-1)^popc(i&maskZY) * M[i][i^maskY]
        float sx = 0.f, sy = 0.f;
#pragma unroll
        for (int i = 0; i < 16; ++i) {
            const float sgn = (__popc(i & maskZY) & 1) ? -1.f : 1.f;
            const c32 m = Mm[i][i ^ maskY];
            sx += sgn * m.x;
            sy += sgn * m.y;
        }
        float re;
        switch (nY & 3) {
            case 0:  re =  sx; break;
            case 1:  re = -sy; break;
            case 2:  re = -sx; break;
            default: re =  sy; break;
        }
        As[t] = re * (1.f / 16.f);
    }
    __syncthreads();

    // --- phase 5: per-sample contraction, SPT samples/thread ---
    float c0[SPT], y0[SPT], c1[SPT], y1[SPT], c2[SPT], y2[SPT], c3[SPT], y3[SPT];
#pragma unroll
    for (int s = 0; s < SPT; ++s) {
        float sn;
        __sincosf(xv[s].x, &sn, &c0[s]); y0[s] = -sn;
        __sincosf(xv[s].y, &sn, &c1[s]); y1[s] = -sn;
        __sincosf(xv[s].z, &sn, &c2[s]); y2[s] = -sn;
        __sincosf(xv[s].w, &sn, &c3[s]); y3[s] = -sn;
    }

    float lvl0[SPT][3];
#pragma unroll
    for (int t0 = 0; t0 < 3; ++t0) {
        float lvl1[SPT][3];
#pragma unroll
        for (int t1 = 0; t1 < 3; ++t1) {
            float v[SPT][3];
#pragma unroll
            for (int t2 = 0; t2 < 3; ++t2) {
                const int b = ((t0 * 3 + t1) * 3 + t2) * 3;
                const float a0 = As[b], a1 = As[b + 1], a2 = As[b + 2];
#pragma unroll
                for (int s = 0; s < SPT; ++s)
                    v[s][t2] = fmaf(y3[s], a2, fmaf(c3[s], a1, a0));
            }
#pragma unroll
            for (int s = 0; s < SPT; ++s)
                lvl1[s][t1] = fmaf(y2[s], v[s][2], fmaf(c2[s], v[s][1], v[s][0]));
        }
#pragma unroll
        for (int s = 0; s < SPT; ++s)
            lvl0[s][t0] = fmaf(y1[s], lvl1[s][2], fmaf(c1[s], lvl1[s][1], lvl1[s][0]));
    }
#pragma unroll
    for (int s = 0; s < SPT; ++s) {
        const int idx = base + s * 256;
        if (idx < M)
            out[idx] = fmaf(y0[s], lvl0[s][2], fmaf(c0[s], lvl0[s][1], lvl0[s][0]));
    }
}

extern "C" void kernel_launch(void* const* d_in, const int* in_sizes, int n_in,
                              void* d_out, int out_size, void* d_ws, size_t ws_size,
                              hipStream_t stream) {
    const float* x = (const float*)d_in[0];      // (64, 8192, 4) f32
    const float* w = (const float*)d_in[1];      // (2, 4, 3) f32
    const int M = in_sizes[0] / 4;               // 524288 samples
    const int blocks = (M + 256 * SPT - 1) / (256 * SPT);
    qq_fused<<<blocks, 256, 0, stream>>>((const float4*)x, w, (float*)d_out, M);
}